// Round 1
// baseline (537.133 us; speedup 1.0000x reference)
//
#include <hip/hip_runtime.h>
#include <math.h>

#define N_NODES 50000
#define N_EDGES 800000
#define HEADS 4
#define HID 32
#define D1 128   // IN_DIM == HEADS*HID
#define D2 64    // EMB
#define NEG_SLOPE 0.2f
#define LN_EPS 1e-5f

__device__ __forceinline__ float lrelu(float x) { return x > 0.f ? x : NEG_SLOPE * x; }

// ---------------- CSR build ----------------
__global__ __launch_bounds__(256) void degree_kernel(const int* __restrict__ dst,
                                                     int* __restrict__ deg) {
    int i = blockIdx.x * blockDim.x + threadIdx.x;
    if (i < N_EDGES) atomicAdd(&deg[dst[i]], 1);
}

__global__ __launch_bounds__(1024) void scan_kernel(const int* __restrict__ deg,
                                                    int* __restrict__ row_ptr) {
    __shared__ int lds[1024];
    __shared__ int carry;
    int tid = threadIdx.x;
    if (tid == 0) carry = 0;
    __syncthreads();
    for (int base = 0; base < N_NODES; base += 1024) {
        int i = base + tid;
        int v = (i < N_NODES) ? deg[i] : 0;
        lds[tid] = v;
        __syncthreads();
        for (int off = 1; off < 1024; off <<= 1) {
            int t = (tid >= off) ? lds[tid - off] : 0;
            __syncthreads();
            lds[tid] += t;
            __syncthreads();
        }
        if (i < N_NODES) row_ptr[i] = carry + lds[tid] - v;  // exclusive scan
        __syncthreads();
        if (tid == 0) carry += lds[1023];
        __syncthreads();
    }
    if (tid == 0) row_ptr[N_NODES] = carry;
}

__global__ __launch_bounds__(256) void scatter_kernel(const int* __restrict__ src,
                                                      const int* __restrict__ dst,
                                                      const int* __restrict__ row_ptr,
                                                      int* __restrict__ cursor,
                                                      int* __restrict__ col) {
    int i = blockIdx.x * blockDim.x + threadIdx.x;
    if (i < N_EDGES) {
        int d = dst[i];
        int pos = row_ptr[d] + atomicAdd(&cursor[d], 1);
        col[pos] = src[i];
    }
}

// ---------------- GEMM: Y[r,c] = sum_k X[r,k] * W[k,c], K=128 ----------------
template <int COLS, int ROWS_PER_BLOCK>
__global__ __launch_bounds__(256) void gemm_kernel(const float* __restrict__ X,
                                                   const float* __restrict__ W,
                                                   float* __restrict__ Y) {
    constexpr int CG = COLS / 16;            // col groups (16 cols each)
    constexpr int RG = 256 / CG;             // row groups
    constexpr int RPT = ROWS_PER_BLOCK / RG; // rows per thread
    __shared__ float Wlds[128 * COLS];
    for (int i = threadIdx.x; i < 128 * COLS; i += 256) Wlds[i] = W[i];
    __syncthreads();

    int cg = threadIdx.x % CG;
    int rg = threadIdx.x / CG;
    int r0 = blockIdx.x * ROWS_PER_BLOCK + rg * RPT;
    int c0 = cg * 16;

    float acc[RPT][16];
#pragma unroll
    for (int i = 0; i < RPT; ++i)
#pragma unroll
        for (int j = 0; j < 16; ++j) acc[i][j] = 0.f;

    const float* xrow[RPT];
#pragma unroll
    for (int i = 0; i < RPT; ++i) {
        int ri = r0 + i;
        if (ri >= N_NODES) ri = N_NODES - 1;  // clamp; store is guarded
        xrow[i] = X + (size_t)ri * 128;
    }

    for (int k = 0; k < 128; ++k) {
        const float4 w0 = *(const float4*)&Wlds[k * COLS + c0 + 0];
        const float4 w1 = *(const float4*)&Wlds[k * COLS + c0 + 4];
        const float4 w2 = *(const float4*)&Wlds[k * COLS + c0 + 8];
        const float4 w3 = *(const float4*)&Wlds[k * COLS + c0 + 12];
#pragma unroll
        for (int i = 0; i < RPT; ++i) {
            float xv = xrow[i][k];
            acc[i][0]  += xv * w0.x; acc[i][1]  += xv * w0.y;
            acc[i][2]  += xv * w0.z; acc[i][3]  += xv * w0.w;
            acc[i][4]  += xv * w1.x; acc[i][5]  += xv * w1.y;
            acc[i][6]  += xv * w1.z; acc[i][7]  += xv * w1.w;
            acc[i][8]  += xv * w2.x; acc[i][9]  += xv * w2.y;
            acc[i][10] += xv * w2.z; acc[i][11] += xv * w2.w;
            acc[i][12] += xv * w3.x; acc[i][13] += xv * w3.y;
            acc[i][14] += xv * w3.z; acc[i][15] += xv * w3.w;
        }
    }

#pragma unroll
    for (int i = 0; i < RPT; ++i) {
        int r = r0 + i;
        if (r < N_NODES) {
            float* yp = Y + (size_t)r * COLS + c0;
            *(float4*)(yp + 0)  = make_float4(acc[i][0], acc[i][1], acc[i][2], acc[i][3]);
            *(float4*)(yp + 4)  = make_float4(acc[i][4], acc[i][5], acc[i][6], acc[i][7]);
            *(float4*)(yp + 8)  = make_float4(acc[i][8], acc[i][9], acc[i][10], acc[i][11]);
            *(float4*)(yp + 12) = make_float4(acc[i][12], acc[i][13], acc[i][14], acc[i][15]);
        }
    }
}

// ---------------- attention coefficients, layer 1 (4 heads x 32) ----------------
__global__ __launch_bounds__(256) void att1_kernel(const float* __restrict__ h,
                                                   const float* __restrict__ att_src,
                                                   const float* __restrict__ att_dst,
                                                   float* __restrict__ a_s,
                                                   float* __restrict__ a_d) {
    int gt = blockIdx.x * blockDim.x + threadIdx.x;
    int n = gt >> 6;
    if (n >= N_NODES) return;
    int lane = threadIdx.x & 63;
    int c = 2 * lane;
    int head = lane >> 4;
    int cl = c & 31;
    float2 v  = *(const float2*)&h[(size_t)n * 128 + c];
    float2 as = *(const float2*)&att_src[head * 32 + cl];
    float2 ad = *(const float2*)&att_dst[head * 32 + cl];
    float ps = v.x * as.x + v.y * as.y;
    float pd = v.x * ad.x + v.y * ad.y;
#pragma unroll
    for (int m = 1; m < 16; m <<= 1) {
        ps += __shfl_xor(ps, m, 64);
        pd += __shfl_xor(pd, m, 64);
    }
    if ((lane & 15) == 0) {
        a_s[n * 4 + head] = ps;
        a_d[n * 4 + head] = pd;
    }
}

// ---------------- attention coefficients, layer 2 (1 head x 64) ----------------
__global__ __launch_bounds__(256) void att2_kernel(const float* __restrict__ h,
                                                   const float* __restrict__ att_src,
                                                   const float* __restrict__ att_dst,
                                                   float* __restrict__ a_s,
                                                   float* __restrict__ a_d) {
    int gt = blockIdx.x * blockDim.x + threadIdx.x;
    int n = gt >> 6;
    if (n >= N_NODES) return;
    int lane = threadIdx.x & 63;
    float v = h[(size_t)n * 64 + lane];
    float ps = v * att_src[lane];
    float pd = v * att_dst[lane];
#pragma unroll
    for (int m = 1; m < 64; m <<= 1) {
        ps += __shfl_xor(ps, m, 64);
        pd += __shfl_xor(pd, m, 64);
    }
    if (lane == 0) {
        a_s[n] = ps;
        a_d[n] = pd;
    }
}

// ---------------- aggregation layer 1: softmax + gather + bias + LN + ReLU ----------------
__global__ __launch_bounds__(256) void agg1_kernel(const float* __restrict__ h,
                                                   const float* __restrict__ a_s,
                                                   const float* __restrict__ a_d,
                                                   const int* __restrict__ row_ptr,
                                                   const int* __restrict__ col,
                                                   const float* __restrict__ b1,
                                                   const float* __restrict__ gamma,
                                                   const float* __restrict__ beta,
                                                   float* __restrict__ out) {
    int gt = blockIdx.x * blockDim.x + threadIdx.x;
    int n = gt >> 6;
    if (n >= N_NODES) return;
    int lane = threadIdx.x & 63;
    int head = lane >> 4;
    int c = 2 * lane;

    float ad0 = a_d[n * 4 + 0], ad1 = a_d[n * 4 + 1];
    float ad2 = a_d[n * 4 + 2], ad3 = a_d[n * 4 + 3];
    int beg = row_ptr[n], end = row_ptr[n + 1];

    // pass 1: softmax denominators, all 4 heads, edges strided across lanes
    float den0 = 0.f, den1 = 0.f, den2 = 0.f, den3 = 0.f;
    for (int j = beg + lane; j < end; j += 64) {
        int s = col[j];
        const float* asp = &a_s[s * 4];
        den0 += __expf(lrelu(asp[0] + ad0));
        den1 += __expf(lrelu(asp[1] + ad1));
        den2 += __expf(lrelu(asp[2] + ad2));
        den3 += __expf(lrelu(asp[3] + ad3));
    }
#pragma unroll
    for (int m = 1; m < 64; m <<= 1) {
        den0 += __shfl_xor(den0, m, 64);
        den1 += __shfl_xor(den1, m, 64);
        den2 += __shfl_xor(den2, m, 64);
        den3 += __shfl_xor(den3, m, 64);
    }
    float adh = (head == 0) ? ad0 : (head == 1) ? ad1 : (head == 2) ? ad2 : ad3;
    float wself = __expf(lrelu(a_s[n * 4 + head] + adh));
    float den = ((head == 0) ? den0 : (head == 1) ? den1 : (head == 2) ? den2 : den3) + wself;

    // pass 2: unnormalized weighted aggregation (2 channels / lane)
    float accx = 0.f, accy = 0.f;
    for (int j = beg; j < end; ++j) {
        int s = col[j];
        float w = __expf(lrelu(a_s[s * 4 + head] + adh));
        float2 hv = *(const float2*)&h[(size_t)s * 128 + c];
        accx += w * hv.x;
        accy += w * hv.y;
    }
    {
        float2 hv = *(const float2*)&h[(size_t)n * 128 + c];
        accx += wself * hv.x;
        accy += wself * hv.y;
    }
    float inv = 1.f / den;
    float vx = accx * inv + b1[c];
    float vy = accy * inv + b1[c + 1];

    // LayerNorm over 128 + ReLU
    float s1 = vx + vy, s2 = vx * vx + vy * vy;
#pragma unroll
    for (int m = 1; m < 64; m <<= 1) {
        s1 += __shfl_xor(s1, m, 64);
        s2 += __shfl_xor(s2, m, 64);
    }
    float mean = s1 * (1.f / 128.f);
    float var = s2 * (1.f / 128.f) - mean * mean;
    float r = rsqrtf(var + LN_EPS);
    float ox = fmaxf(0.f, (vx - mean) * r * gamma[c] + beta[c]);
    float oy = fmaxf(0.f, (vy - mean) * r * gamma[c + 1] + beta[c + 1]);
    *(float2*)&out[(size_t)n * 128 + c] = make_float2(ox, oy);
}

// ---------------- aggregation layer 2: softmax + gather + bias + LN ----------------
__global__ __launch_bounds__(256) void agg2_kernel(const float* __restrict__ h,
                                                   const float* __restrict__ a_s,
                                                   const float* __restrict__ a_d,
                                                   const int* __restrict__ row_ptr,
                                                   const int* __restrict__ col,
                                                   const float* __restrict__ b2,
                                                   const float* __restrict__ gamma,
                                                   const float* __restrict__ beta,
                                                   float* __restrict__ out) {
    int gt = blockIdx.x * blockDim.x + threadIdx.x;
    int n = gt >> 6;
    if (n >= N_NODES) return;
    int lane = threadIdx.x & 63;

    float adh = a_d[n];
    int beg = row_ptr[n], end = row_ptr[n + 1];

    float den = 0.f;
    for (int j = beg + lane; j < end; j += 64) {
        den += __expf(lrelu(a_s[col[j]] + adh));
    }
#pragma unroll
    for (int m = 1; m < 64; m <<= 1) den += __shfl_xor(den, m, 64);
    float wself = __expf(lrelu(a_s[n] + adh));
    den += wself;

    float acc = 0.f;
    for (int j = beg; j < end; ++j) {
        int s = col[j];
        float w = __expf(lrelu(a_s[s] + adh));
        acc += w * h[(size_t)s * 64 + lane];
    }
    acc += wself * h[(size_t)n * 64 + lane];

    float v = acc / den + b2[lane];

    float s1 = v, s2 = v * v;
#pragma unroll
    for (int m = 1; m < 64; m <<= 1) {
        s1 += __shfl_xor(s1, m, 64);
        s2 += __shfl_xor(s2, m, 64);
    }
    float mean = s1 * (1.f / 64.f);
    float var = s2 * (1.f / 64.f) - mean * mean;
    float r = rsqrtf(var + LN_EPS);
    out[(size_t)n * 64 + lane] = (v - mean) * r * gamma[lane] + beta[lane];
}

// ---------------- host ----------------
extern "C" void kernel_launch(void* const* d_in, const int* in_sizes, int n_in,
                              void* d_out, int out_size, void* d_ws, size_t ws_size,
                              hipStream_t stream) {
    const float* x        = (const float*)d_in[0];
    const int*   ei       = (const int*)d_in[1];
    const float* W1       = (const float*)d_in[2];
    const float* att_src1 = (const float*)d_in[3];
    const float* att_dst1 = (const float*)d_in[4];
    const float* b1       = (const float*)d_in[5];
    const float* gamma1   = (const float*)d_in[6];
    const float* beta1    = (const float*)d_in[7];
    const float* W2       = (const float*)d_in[8];
    const float* att_src2 = (const float*)d_in[9];
    const float* att_dst2 = (const float*)d_in[10];
    const float* b2       = (const float*)d_in[11];
    const float* gamma2   = (const float*)d_in[12];
    const float* beta2    = (const float*)d_in[13];
    const int* src = ei;
    const int* dst = ei + N_EDGES;
    float* out = (float*)d_out;

    char* ws = (char*)d_ws;
    size_t off = 0;
    auto alloc = [&](size_t bytes) -> void* {
        void* p = ws + off;
        off += bytes;
        off = (off + 255) & ~(size_t)255;
        return p;
    };
    float* h1pre  = (float*)alloc((size_t)N_NODES * 128 * 4);
    float* a_s1   = (float*)alloc((size_t)N_NODES * 4 * 4);
    float* a_d1   = (float*)alloc((size_t)N_NODES * 4 * 4);
    float* h1n    = (float*)alloc((size_t)N_NODES * 128 * 4);
    float* h2pre  = (float*)alloc((size_t)N_NODES * 64 * 4);
    float* a_s2   = (float*)alloc((size_t)N_NODES * 4);
    float* a_d2   = (float*)alloc((size_t)N_NODES * 4);
    int* deg      = (int*)alloc((size_t)N_NODES * 4);
    int* row_ptr  = (int*)alloc((size_t)(N_NODES + 1) * 4);
    int* col      = (int*)alloc((size_t)N_EDGES * 4);
    int* cursor   = (int*)alloc((size_t)N_NODES * 4);

    hipMemsetAsync(deg, 0, (size_t)N_NODES * 4, stream);
    hipMemsetAsync(cursor, 0, (size_t)N_NODES * 4, stream);

    const int EB = (N_EDGES + 255) / 256;
    const int WB = (N_NODES * 64 + 255) / 256;  // one wave per node, 4 waves/block

    degree_kernel<<<EB, 256, 0, stream>>>(dst, deg);
    scan_kernel<<<1, 1024, 0, stream>>>(deg, row_ptr);
    scatter_kernel<<<EB, 256, 0, stream>>>(src, dst, row_ptr, cursor, col);

    // layer 1
    gemm_kernel<128, 128><<<(N_NODES + 127) / 128, 256, 0, stream>>>(x, W1, h1pre);
    att1_kernel<<<WB, 256, 0, stream>>>(h1pre, att_src1, att_dst1, a_s1, a_d1);
    agg1_kernel<<<WB, 256, 0, stream>>>(h1pre, a_s1, a_d1, row_ptr, col, b1, gamma1, beta1, h1n);

    // layer 2
    gemm_kernel<64, 256><<<(N_NODES + 255) / 256, 256, 0, stream>>>(h1n, W2, h2pre);
    att2_kernel<<<WB, 256, 0, stream>>>(h2pre, att_src2, att_dst2, a_s2, a_d2);
    agg2_kernel<<<WB, 256, 0, stream>>>(h2pre, a_s2, a_d2, row_ptr, col, b2, gamma2, beta2, out);
}

// Round 2
// 437.314 us; speedup vs baseline: 1.2283x; 1.2283x over previous
//
#include <hip/hip_runtime.h>
#include <hip/hip_bf16.h>
#include <math.h>

#define N_NODES 50000
#define N_EDGES 800000
#define HEADS 4
#define HID 32
#define D1 128
#define D2 64
#define NEG_SLOPE 0.2f
#define LN_EPS 1e-5f

#define NB_SCAN ((N_NODES + 255) / 256)

__device__ __forceinline__ float lrelu(float x) { return x > 0.f ? x : NEG_SLOPE * x; }
__device__ __forceinline__ float bf2f(__hip_bfloat16 v) { return __bfloat162float(v); }

// ---------------- CSR build ----------------
__global__ __launch_bounds__(256) void degree_kernel(const int* __restrict__ dst,
                                                     int* __restrict__ deg) {
    int i = blockIdx.x * blockDim.x + threadIdx.x;
    if (i < N_EDGES) atomicAdd(&deg[dst[i]], 1);
}

// per-block exclusive scan; block sums out
__global__ __launch_bounds__(256) void scan1_kernel(const int* __restrict__ deg,
                                                    int* __restrict__ row_ptr,
                                                    int* __restrict__ bsum) {
    int i = blockIdx.x * 256 + threadIdx.x;
    int v = (i < N_NODES) ? deg[i] : 0;
    int lane = threadIdx.x & 63;
    int w = threadIdx.x >> 6;
    int x = v;
#pragma unroll
    for (int off = 1; off < 64; off <<= 1) {
        int t = __shfl_up(x, off, 64);
        if (lane >= off) x += t;
    }
    __shared__ int wsum[4];
    if (lane == 63) wsum[w] = x;
    __syncthreads();
    int wo = 0;
    if (w > 0) wo += wsum[0];
    if (w > 1) wo += wsum[1];
    if (w > 2) wo += wsum[2];
    if (i < N_NODES) row_ptr[i] = x - v + wo;  // local exclusive
    if (threadIdx.x == 255) bsum[blockIdx.x] = x + wo;  // block total
}

// exclusive scan of block sums (NB_SCAN <= 256)
__global__ __launch_bounds__(256) void scan2_kernel(const int* __restrict__ bsum,
                                                    int* __restrict__ boff) {
    int i = threadIdx.x;
    int v = (i < NB_SCAN) ? bsum[i] : 0;
    int lane = threadIdx.x & 63;
    int w = threadIdx.x >> 6;
    int x = v;
#pragma unroll
    for (int off = 1; off < 64; off <<= 1) {
        int t = __shfl_up(x, off, 64);
        if (lane >= off) x += t;
    }
    __shared__ int wsum[4];
    if (lane == 63) wsum[w] = x;
    __syncthreads();
    int wo = 0;
    if (w > 0) wo += wsum[0];
    if (w > 1) wo += wsum[1];
    if (w > 2) wo += wsum[2];
    if (i < NB_SCAN) boff[i] = x - v + wo;
}

__global__ __launch_bounds__(256) void scan3_kernel(int* __restrict__ row_ptr,
                                                    const int* __restrict__ boff) {
    int i = blockIdx.x * 256 + threadIdx.x;
    if (i < N_NODES) row_ptr[i] += boff[blockIdx.x];
    if (i == 0) row_ptr[N_NODES] = N_EDGES;
}

__global__ __launch_bounds__(256) void scatter_kernel(const int* __restrict__ src,
                                                      const int* __restrict__ dst,
                                                      const int* __restrict__ row_ptr,
                                                      int* __restrict__ cursor,
                                                      int* __restrict__ col) {
    int i = blockIdx.x * blockDim.x + threadIdx.x;
    if (i < N_EDGES) {
        int d = dst[i];
        int pos = row_ptr[d] + atomicAdd(&cursor[d], 1);
        col[pos] = src[i];
    }
}

// ---------------- GEMM: Y[r,c] = sum_k X[r,k] * W[k,c], K=128, bf16 output ----------------
template <int COLS, int ROWS_PER_BLOCK>
__global__ __launch_bounds__(256) void gemm_kernel(const float* __restrict__ X,
                                                   const float* __restrict__ W,
                                                   __hip_bfloat16* __restrict__ Y) {
    constexpr int CG = COLS / 16;
    constexpr int RG = 256 / CG;
    constexpr int RPT = ROWS_PER_BLOCK / RG;
    __shared__ float Wlds[128 * COLS];
    for (int i = threadIdx.x; i < 128 * COLS; i += 256) Wlds[i] = W[i];
    __syncthreads();

    int cg = threadIdx.x % CG;
    int rg = threadIdx.x / CG;
    int r0 = blockIdx.x * ROWS_PER_BLOCK + rg * RPT;
    int c0 = cg * 16;

    float acc[RPT][16];
#pragma unroll
    for (int i = 0; i < RPT; ++i)
#pragma unroll
        for (int j = 0; j < 16; ++j) acc[i][j] = 0.f;

    const float* xrow[RPT];
#pragma unroll
    for (int i = 0; i < RPT; ++i) {
        int ri = r0 + i;
        if (ri >= N_NODES) ri = N_NODES - 1;
        xrow[i] = X + (size_t)ri * 128;
    }

    for (int k = 0; k < 128; ++k) {
        const float4 w0 = *(const float4*)&Wlds[k * COLS + c0 + 0];
        const float4 w1 = *(const float4*)&Wlds[k * COLS + c0 + 4];
        const float4 w2 = *(const float4*)&Wlds[k * COLS + c0 + 8];
        const float4 w3 = *(const float4*)&Wlds[k * COLS + c0 + 12];
#pragma unroll
        for (int i = 0; i < RPT; ++i) {
            float xv = xrow[i][k];
            acc[i][0]  += xv * w0.x; acc[i][1]  += xv * w0.y;
            acc[i][2]  += xv * w0.z; acc[i][3]  += xv * w0.w;
            acc[i][4]  += xv * w1.x; acc[i][5]  += xv * w1.y;
            acc[i][6]  += xv * w1.z; acc[i][7]  += xv * w1.w;
            acc[i][8]  += xv * w2.x; acc[i][9]  += xv * w2.y;
            acc[i][10] += xv * w2.z; acc[i][11] += xv * w2.w;
            acc[i][12] += xv * w3.x; acc[i][13] += xv * w3.y;
            acc[i][14] += xv * w3.z; acc[i][15] += xv * w3.w;
        }
    }

#pragma unroll
    for (int i = 0; i < RPT; ++i) {
        int r = r0 + i;
        if (r < N_NODES) {
            __hip_bfloat162* yp = (__hip_bfloat162*)(Y + (size_t)r * COLS + c0);
#pragma unroll
            for (int j = 0; j < 8; ++j) {
                __hip_bfloat162 p;
                p.x = __float2bfloat16(acc[i][2 * j]);
                p.y = __float2bfloat16(acc[i][2 * j + 1]);
                yp[j] = p;
            }
        }
    }
}

// ---------------- attention coefficients, layer 1 (4 heads x 32) ----------------
__global__ __launch_bounds__(256) void att1_kernel(const __hip_bfloat16* __restrict__ h,
                                                   const float* __restrict__ att_src,
                                                   const float* __restrict__ att_dst,
                                                   float* __restrict__ a_s,
                                                   float* __restrict__ a_d) {
    int gt = blockIdx.x * blockDim.x + threadIdx.x;
    int n = gt >> 6;
    if (n >= N_NODES) return;
    int lane = threadIdx.x & 63;
    int c = 2 * lane;
    int head = lane >> 4;
    int cl = c & 31;
    __hip_bfloat162 hv = ((const __hip_bfloat162*)h)[(size_t)n * 64 + lane];
    float vx = bf2f(hv.x), vy = bf2f(hv.y);
    float2 as = *(const float2*)&att_src[head * 32 + cl];
    float2 ad = *(const float2*)&att_dst[head * 32 + cl];
    float ps = vx * as.x + vy * as.y;
    float pd = vx * ad.x + vy * ad.y;
#pragma unroll
    for (int m = 1; m < 16; m <<= 1) {
        ps += __shfl_xor(ps, m, 64);
        pd += __shfl_xor(pd, m, 64);
    }
    if ((lane & 15) == 0) {
        a_s[n * 4 + head] = ps;
        a_d[n * 4 + head] = pd;
    }
}

// ---------------- attention coefficients, layer 2 (1 head x 64) ----------------
__global__ __launch_bounds__(256) void att2_kernel(const __hip_bfloat16* __restrict__ h,
                                                   const float* __restrict__ att_src,
                                                   const float* __restrict__ att_dst,
                                                   float* __restrict__ a_s,
                                                   float* __restrict__ a_d) {
    int gt = blockIdx.x * blockDim.x + threadIdx.x;
    int n = gt >> 6;
    if (n >= N_NODES) return;
    int lane = threadIdx.x & 63;
    float v = bf2f(h[(size_t)n * 64 + lane]);
    float ps = v * att_src[lane];
    float pd = v * att_dst[lane];
#pragma unroll
    for (int m = 1; m < 64; m <<= 1) {
        ps += __shfl_xor(ps, m, 64);
        pd += __shfl_xor(pd, m, 64);
    }
    if (lane == 0) {
        a_s[n] = ps;
        a_d[n] = pd;
    }
}

// ---------------- aggregation layer 1: softmax + gather + bias + LN + ReLU ----------------
__global__ __launch_bounds__(256) void agg1_kernel(const __hip_bfloat16* __restrict__ h,
                                                   const float* __restrict__ a_s,
                                                   const float* __restrict__ a_d,
                                                   const int* __restrict__ row_ptr,
                                                   const int* __restrict__ col,
                                                   const float* __restrict__ b1,
                                                   const float* __restrict__ gamma,
                                                   const float* __restrict__ beta,
                                                   float* __restrict__ out) {
    int gt = blockIdx.x * blockDim.x + threadIdx.x;
    int n = gt >> 6;
    if (n >= N_NODES) return;
    int lane = threadIdx.x & 63;
    int head = lane >> 4;
    int c = 2 * lane;

    float ad0 = a_d[n * 4 + 0], ad1 = a_d[n * 4 + 1];
    float ad2 = a_d[n * 4 + 2], ad3 = a_d[n * 4 + 3];
    int beg = row_ptr[n], end = row_ptr[n + 1];

    float den0 = 0.f, den1 = 0.f, den2 = 0.f, den3 = 0.f;
    for (int j = beg + lane; j < end; j += 64) {
        int s = col[j];
        const float* asp = &a_s[s * 4];
        den0 += __expf(lrelu(asp[0] + ad0));
        den1 += __expf(lrelu(asp[1] + ad1));
        den2 += __expf(lrelu(asp[2] + ad2));
        den3 += __expf(lrelu(asp[3] + ad3));
    }
#pragma unroll
    for (int m = 1; m < 64; m <<= 1) {
        den0 += __shfl_xor(den0, m, 64);
        den1 += __shfl_xor(den1, m, 64);
        den2 += __shfl_xor(den2, m, 64);
        den3 += __shfl_xor(den3, m, 64);
    }
    float adh = (head == 0) ? ad0 : (head == 1) ? ad1 : (head == 2) ? ad2 : ad3;
    float wself = __expf(lrelu(a_s[n * 4 + head] + adh));
    float den = ((head == 0) ? den0 : (head == 1) ? den1 : (head == 2) ? den2 : den3) + wself;

    float accx = 0.f, accy = 0.f;
    for (int j = beg; j < end; ++j) {
        int s = col[j];
        float w = __expf(lrelu(a_s[s * 4 + head] + adh));
        __hip_bfloat162 hv = ((const __hip_bfloat162*)h)[(size_t)s * 64 + lane];
        accx += w * bf2f(hv.x);
        accy += w * bf2f(hv.y);
    }
    {
        __hip_bfloat162 hv = ((const __hip_bfloat162*)h)[(size_t)n * 64 + lane];
        accx += wself * bf2f(hv.x);
        accy += wself * bf2f(hv.y);
    }
    float inv = 1.f / den;
    float vx = accx * inv + b1[c];
    float vy = accy * inv + b1[c + 1];

    float s1 = vx + vy, s2 = vx * vx + vy * vy;
#pragma unroll
    for (int m = 1; m < 64; m <<= 1) {
        s1 += __shfl_xor(s1, m, 64);
        s2 += __shfl_xor(s2, m, 64);
    }
    float mean = s1 * (1.f / 128.f);
    float var = s2 * (1.f / 128.f) - mean * mean;
    float r = rsqrtf(var + LN_EPS);
    float ox = fmaxf(0.f, (vx - mean) * r * gamma[c] + beta[c]);
    float oy = fmaxf(0.f, (vy - mean) * r * gamma[c + 1] + beta[c + 1]);
    *(float2*)&out[(size_t)n * 128 + c] = make_float2(ox, oy);
}

// ---------------- aggregation layer 2: softmax + gather + bias + LN ----------------
__global__ __launch_bounds__(256) void agg2_kernel(const __hip_bfloat16* __restrict__ h,
                                                   const float* __restrict__ a_s,
                                                   const float* __restrict__ a_d,
                                                   const int* __restrict__ row_ptr,
                                                   const int* __restrict__ col,
                                                   const float* __restrict__ b2,
                                                   const float* __restrict__ gamma,
                                                   const float* __restrict__ beta,
                                                   float* __restrict__ out) {
    int gt = blockIdx.x * blockDim.x + threadIdx.x;
    int n = gt >> 6;
    if (n >= N_NODES) return;
    int lane = threadIdx.x & 63;

    float adh = a_d[n];
    int beg = row_ptr[n], end = row_ptr[n + 1];

    float den = 0.f;
    for (int j = beg + lane; j < end; j += 64) {
        den += __expf(lrelu(a_s[col[j]] + adh));
    }
#pragma unroll
    for (int m = 1; m < 64; m <<= 1) den += __shfl_xor(den, m, 64);
    float wself = __expf(lrelu(a_s[n] + adh));
    den += wself;

    float acc = 0.f;
    for (int j = beg; j < end; ++j) {
        int s = col[j];
        float w = __expf(lrelu(a_s[s] + adh));
        acc += w * bf2f(h[(size_t)s * 64 + lane]);
    }
    acc += wself * bf2f(h[(size_t)n * 64 + lane]);

    float v = acc / den + b2[lane];

    float s1 = v, s2 = v * v;
#pragma unroll
    for (int m = 1; m < 64; m <<= 1) {
        s1 += __shfl_xor(s1, m, 64);
        s2 += __shfl_xor(s2, m, 64);
    }
    float mean = s1 * (1.f / 64.f);
    float var = s2 * (1.f / 64.f) - mean * mean;
    float r = rsqrtf(var + LN_EPS);
    out[(size_t)n * 64 + lane] = (v - mean) * r * gamma[lane] + beta[lane];
}

// ---------------- host ----------------
extern "C" void kernel_launch(void* const* d_in, const int* in_sizes, int n_in,
                              void* d_out, int out_size, void* d_ws, size_t ws_size,
                              hipStream_t stream) {
    const float* x        = (const float*)d_in[0];
    const int*   ei       = (const int*)d_in[1];
    const float* W1       = (const float*)d_in[2];
    const float* att_src1 = (const float*)d_in[3];
    const float* att_dst1 = (const float*)d_in[4];
    const float* b1       = (const float*)d_in[5];
    const float* gamma1   = (const float*)d_in[6];
    const float* beta1    = (const float*)d_in[7];
    const float* W2       = (const float*)d_in[8];
    const float* att_src2 = (const float*)d_in[9];
    const float* att_dst2 = (const float*)d_in[10];
    const float* b2       = (const float*)d_in[11];
    const float* gamma2   = (const float*)d_in[12];
    const float* beta2    = (const float*)d_in[13];
    const int* src = ei;
    const int* dst = ei + N_EDGES;
    float* out = (float*)d_out;

    char* ws = (char*)d_ws;
    size_t off = 0;
    auto alloc = [&](size_t bytes) -> void* {
        void* p = ws + off;
        off += bytes;
        off = (off + 255) & ~(size_t)255;
        return p;
    };
    __hip_bfloat16* h1pre = (__hip_bfloat16*)alloc((size_t)N_NODES * 128 * 2);
    __hip_bfloat16* h2pre = (__hip_bfloat16*)alloc((size_t)N_NODES * 64 * 2);
    float* a_s1   = (float*)alloc((size_t)N_NODES * 4 * 4);
    float* a_d1   = (float*)alloc((size_t)N_NODES * 4 * 4);
    float* h1n    = (float*)alloc((size_t)N_NODES * 128 * 4);
    float* a_s2   = (float*)alloc((size_t)N_NODES * 4);
    float* a_d2   = (float*)alloc((size_t)N_NODES * 4);
    int* deg      = (int*)alloc((size_t)N_NODES * 4);
    int* row_ptr  = (int*)alloc((size_t)(N_NODES + 1) * 4);
    int* col      = (int*)alloc((size_t)N_EDGES * 4);
    int* cursor   = (int*)alloc((size_t)N_NODES * 4);
    int* bsum     = (int*)alloc((size_t)NB_SCAN * 4);
    int* boff     = (int*)alloc((size_t)NB_SCAN * 4);

    hipMemsetAsync(deg, 0, (size_t)N_NODES * 4, stream);
    hipMemsetAsync(cursor, 0, (size_t)N_NODES * 4, stream);

    const int EB = (N_EDGES + 255) / 256;
    const int WB = (N_NODES * 64 + 255) / 256;  // one wave per node

    degree_kernel<<<EB, 256, 0, stream>>>(dst, deg);
    scan1_kernel<<<NB_SCAN, 256, 0, stream>>>(deg, row_ptr, bsum);
    scan2_kernel<<<1, 256, 0, stream>>>(bsum, boff);
    scan3_kernel<<<NB_SCAN, 256, 0, stream>>>(row_ptr, boff);
    scatter_kernel<<<EB, 256, 0, stream>>>(src, dst, row_ptr, cursor, col);

    // layer 1
    gemm_kernel<128, 128><<<(N_NODES + 127) / 128, 256, 0, stream>>>(x, W1, h1pre);
    att1_kernel<<<WB, 256, 0, stream>>>(h1pre, att_src1, att_dst1, a_s1, a_d1);
    agg1_kernel<<<WB, 256, 0, stream>>>(h1pre, a_s1, a_d1, row_ptr, col, b1, gamma1, beta1, h1n);

    // layer 2
    gemm_kernel<64, 256><<<(N_NODES + 255) / 256, 256, 0, stream>>>(h1n, W2, h2pre);
    att2_kernel<<<WB, 256, 0, stream>>>(h2pre, att_src2, att_dst2, a_s2, a_d2);
    agg2_kernel<<<WB, 256, 0, stream>>>(h2pre, a_s2, a_d2, row_ptr, col, b2, gamma2, beta2, out);
}

// Round 3
// 340.708 us; speedup vs baseline: 1.5765x; 1.2835x over previous
//
#include <hip/hip_runtime.h>
#include <hip/hip_bf16.h>
#include <math.h>

#define N_NODES 50000
#define N_EDGES 800000
#define HEADS 4
#define HID 32
#define D1 128
#define D2 64
#define NEG_SLOPE 0.2f
#define LN_EPS 1e-5f

#define NB_SCAN ((N_NODES + 255) / 256)
#define CAP 64  // LDS-cached edges per row; Poisson(16) => P(deg>64) ~ 0, fallback handles rest

__device__ __forceinline__ float lrelu(float x) { return x > 0.f ? x : NEG_SLOPE * x; }
__device__ __forceinline__ float bf2f(__hip_bfloat16 v) { return __bfloat162float(v); }

// ---------------- CSR build ----------------
__global__ __launch_bounds__(256) void degree_kernel(const int* __restrict__ dst,
                                                     int* __restrict__ deg) {
    int i = blockIdx.x * blockDim.x + threadIdx.x;
    if (i < N_EDGES) atomicAdd(&deg[dst[i]], 1);
}

__global__ __launch_bounds__(256) void scan1_kernel(const int* __restrict__ deg,
                                                    int* __restrict__ row_ptr,
                                                    int* __restrict__ bsum) {
    int i = blockIdx.x * 256 + threadIdx.x;
    int v = (i < N_NODES) ? deg[i] : 0;
    int lane = threadIdx.x & 63;
    int w = threadIdx.x >> 6;
    int x = v;
#pragma unroll
    for (int off = 1; off < 64; off <<= 1) {
        int t = __shfl_up(x, off, 64);
        if (lane >= off) x += t;
    }
    __shared__ int wsum[4];
    if (lane == 63) wsum[w] = x;
    __syncthreads();
    int wo = 0;
    if (w > 0) wo += wsum[0];
    if (w > 1) wo += wsum[1];
    if (w > 2) wo += wsum[2];
    if (i < N_NODES) row_ptr[i] = x - v + wo;
    if (threadIdx.x == 255) bsum[blockIdx.x] = x + wo;
}

__global__ __launch_bounds__(256) void scan2_kernel(const int* __restrict__ bsum,
                                                    int* __restrict__ boff) {
    int i = threadIdx.x;
    int v = (i < NB_SCAN) ? bsum[i] : 0;
    int lane = threadIdx.x & 63;
    int w = threadIdx.x >> 6;
    int x = v;
#pragma unroll
    for (int off = 1; off < 64; off <<= 1) {
        int t = __shfl_up(x, off, 64);
        if (lane >= off) x += t;
    }
    __shared__ int wsum[4];
    if (lane == 63) wsum[w] = x;
    __syncthreads();
    int wo = 0;
    if (w > 0) wo += wsum[0];
    if (w > 1) wo += wsum[1];
    if (w > 2) wo += wsum[2];
    if (i < NB_SCAN) boff[i] = x - v + wo;
}

__global__ __launch_bounds__(256) void scan3_kernel(int* __restrict__ row_ptr,
                                                    const int* __restrict__ boff) {
    int i = blockIdx.x * 256 + threadIdx.x;
    if (i < N_NODES) row_ptr[i] += boff[blockIdx.x];
    if (i == 0) row_ptr[N_NODES] = N_EDGES;
}

__global__ __launch_bounds__(256) void scatter_kernel(const int* __restrict__ src,
                                                      const int* __restrict__ dst,
                                                      const int* __restrict__ row_ptr,
                                                      int* __restrict__ cursor,
                                                      int* __restrict__ col) {
    int i = blockIdx.x * blockDim.x + threadIdx.x;
    if (i < N_EDGES) {
        int d = dst[i];
        int pos = row_ptr[d] + atomicAdd(&cursor[d], 1);
        col[pos] = src[i];
    }
}

// ---------------- GEMM: Y = X(N,128) * W(128,COLS), bf16 output ----------------
template <int COLS, int ROWS_PER_BLOCK>
__global__ __launch_bounds__(256) void gemm_kernel(const float* __restrict__ X,
                                                   const float* __restrict__ W,
                                                   __hip_bfloat16* __restrict__ Y) {
    constexpr int CG = COLS / 16;
    constexpr int RG = 256 / CG;
    constexpr int RPT = ROWS_PER_BLOCK / RG;
    __shared__ float Wlds[128 * COLS];
    for (int i = threadIdx.x; i < 128 * COLS; i += 256) Wlds[i] = W[i];
    __syncthreads();

    int cg = threadIdx.x % CG;
    int rg = threadIdx.x / CG;
    int r0 = blockIdx.x * ROWS_PER_BLOCK + rg * RPT;
    int c0 = cg * 16;

    float acc[RPT][16];
#pragma unroll
    for (int i = 0; i < RPT; ++i)
#pragma unroll
        for (int j = 0; j < 16; ++j) acc[i][j] = 0.f;

    const float* xrow[RPT];
#pragma unroll
    for (int i = 0; i < RPT; ++i) {
        int ri = r0 + i;
        if (ri >= N_NODES) ri = N_NODES - 1;
        xrow[i] = X + (size_t)ri * 128;
    }

    for (int k = 0; k < 128; k += 4) {
        float4 xv[RPT];
#pragma unroll
        for (int i = 0; i < RPT; ++i) xv[i] = *(const float4*)&xrow[i][k];
#pragma unroll
        for (int kk = 0; kk < 4; ++kk) {
            const float* wrow = &Wlds[(k + kk) * COLS + c0];
            const float4 w0 = *(const float4*)(wrow + 0);
            const float4 w1 = *(const float4*)(wrow + 4);
            const float4 w2 = *(const float4*)(wrow + 8);
            const float4 w3 = *(const float4*)(wrow + 12);
#pragma unroll
            for (int i = 0; i < RPT; ++i) {
                float xk = (kk == 0) ? xv[i].x : (kk == 1) ? xv[i].y : (kk == 2) ? xv[i].z : xv[i].w;
                acc[i][0]  += xk * w0.x; acc[i][1]  += xk * w0.y;
                acc[i][2]  += xk * w0.z; acc[i][3]  += xk * w0.w;
                acc[i][4]  += xk * w1.x; acc[i][5]  += xk * w1.y;
                acc[i][6]  += xk * w1.z; acc[i][7]  += xk * w1.w;
                acc[i][8]  += xk * w2.x; acc[i][9]  += xk * w2.y;
                acc[i][10] += xk * w2.z; acc[i][11] += xk * w2.w;
                acc[i][12] += xk * w3.x; acc[i][13] += xk * w3.y;
                acc[i][14] += xk * w3.z; acc[i][15] += xk * w3.w;
            }
        }
    }

#pragma unroll
    for (int i = 0; i < RPT; ++i) {
        int r = r0 + i;
        if (r < N_NODES) {
            __hip_bfloat162* yp = (__hip_bfloat162*)(Y + (size_t)r * COLS + c0);
#pragma unroll
            for (int j = 0; j < 8; ++j) {
                __hip_bfloat162 p;
                p.x = __float2bfloat16(acc[i][2 * j]);
                p.y = __float2bfloat16(acc[i][2 * j + 1]);
                yp[j] = p;
            }
        }
    }
}

// ---------------- attention coefficients, layer 1 ----------------
__global__ __launch_bounds__(256) void att1_kernel(const __hip_bfloat16* __restrict__ h,
                                                   const float* __restrict__ att_src,
                                                   const float* __restrict__ att_dst,
                                                   float* __restrict__ a_s,
                                                   float* __restrict__ a_d) {
    int gt = blockIdx.x * blockDim.x + threadIdx.x;
    int n = gt >> 6;
    if (n >= N_NODES) return;
    int lane = threadIdx.x & 63;
    int c = 2 * lane;
    int head = lane >> 4;
    int cl = c & 31;
    __hip_bfloat162 hv = ((const __hip_bfloat162*)h)[(size_t)n * 64 + lane];
    float vx = bf2f(hv.x), vy = bf2f(hv.y);
    float2 as = *(const float2*)&att_src[head * 32 + cl];
    float2 ad = *(const float2*)&att_dst[head * 32 + cl];
    float ps = vx * as.x + vy * as.y;
    float pd = vx * ad.x + vy * ad.y;
#pragma unroll
    for (int m = 1; m < 16; m <<= 1) {
        ps += __shfl_xor(ps, m, 64);
        pd += __shfl_xor(pd, m, 64);
    }
    if ((lane & 15) == 0) {
        a_s[n * 4 + head] = ps;
        a_d[n * 4 + head] = pd;
    }
}

// ---------------- attention coefficients, layer 2 ----------------
__global__ __launch_bounds__(256) void att2_kernel(const __hip_bfloat16* __restrict__ h,
                                                   const float* __restrict__ att_src,
                                                   const float* __restrict__ att_dst,
                                                   float* __restrict__ a_s,
                                                   float* __restrict__ a_d) {
    int gt = blockIdx.x * blockDim.x + threadIdx.x;
    int n = gt >> 6;
    if (n >= N_NODES) return;
    int lane = threadIdx.x & 63;
    float v = bf2f(h[(size_t)n * 64 + lane]);
    float ps = v * att_src[lane];
    float pd = v * att_dst[lane];
#pragma unroll
    for (int m = 1; m < 64; m <<= 1) {
        ps += __shfl_xor(ps, m, 64);
        pd += __shfl_xor(pd, m, 64);
    }
    if (lane == 0) {
        a_s[n] = ps;
        a_d[n] = pd;
    }
}

// ---------------- aggregation layer 1 ----------------
__global__ __launch_bounds__(256) void agg1_kernel(const __hip_bfloat16* __restrict__ h,
                                                   const float* __restrict__ a_s,
                                                   const float* __restrict__ a_d,
                                                   const int* __restrict__ row_ptr,
                                                   const int* __restrict__ col,
                                                   const float* __restrict__ b1,
                                                   const float* __restrict__ gamma,
                                                   const float* __restrict__ beta,
                                                   float* __restrict__ out) {
    __shared__ int colsh[4][CAP];
    __shared__ float wsh[4][CAP * 4];
    int wv = threadIdx.x >> 6;
    int lane = threadIdx.x & 63;
    int n = blockIdx.x * 4 + wv;
    int nn = (n < N_NODES) ? n : N_NODES - 1;
    int head = lane >> 4;
    int c = 2 * lane;

    const float4 ad4 = *(const float4*)&a_d[nn * 4];
    int beg = row_ptr[nn], end = row_ptr[nn + 1];
    int deg = end - beg;

    // pass 1: compute per-edge weights (all heads) once, stash in LDS, reduce dens
    float den0 = 0.f, den1 = 0.f, den2 = 0.f, den3 = 0.f;
    for (int t = lane; t < deg; t += 64) {
        int s = col[beg + t];
        const float4 as4 = *(const float4*)&a_s[s * 4];
        float w0 = __expf(lrelu(as4.x + ad4.x));
        float w1 = __expf(lrelu(as4.y + ad4.y));
        float w2 = __expf(lrelu(as4.z + ad4.z));
        float w3 = __expf(lrelu(as4.w + ad4.w));
        if (t < CAP) {
            colsh[wv][t] = s;
            *(float4*)&wsh[wv][t * 4] = make_float4(w0, w1, w2, w3);
        }
        den0 += w0; den1 += w1; den2 += w2; den3 += w3;
    }
#pragma unroll
    for (int m = 1; m < 64; m <<= 1) {
        den0 += __shfl_xor(den0, m, 64);
        den1 += __shfl_xor(den1, m, 64);
        den2 += __shfl_xor(den2, m, 64);
        den3 += __shfl_xor(den3, m, 64);
    }
    float adh = (head == 0) ? ad4.x : (head == 1) ? ad4.y : (head == 2) ? ad4.z : ad4.w;
    float wself = __expf(lrelu(a_s[nn * 4 + head] + adh));
    float den = ((head == 0) ? den0 : (head == 1) ? den1 : (head == 2) ? den2 : den3) + wself;

    __syncthreads();

    // pass 2: weighted gather, 4 edges in flight
    float ax0 = 0.f, ay0 = 0.f, ax1 = 0.f, ay1 = 0.f;
    int m0 = (deg < CAP) ? deg : CAP;
    int j = 0;
    for (; j + 3 < m0; j += 4) {
        int s0 = colsh[wv][j + 0], s1 = colsh[wv][j + 1];
        int s2 = colsh[wv][j + 2], s3 = colsh[wv][j + 3];
        float w0 = wsh[wv][(j + 0) * 4 + head], w1 = wsh[wv][(j + 1) * 4 + head];
        float w2 = wsh[wv][(j + 2) * 4 + head], w3 = wsh[wv][(j + 3) * 4 + head];
        __hip_bfloat162 h0 = ((const __hip_bfloat162*)h)[(size_t)s0 * 64 + lane];
        __hip_bfloat162 h1 = ((const __hip_bfloat162*)h)[(size_t)s1 * 64 + lane];
        __hip_bfloat162 h2v = ((const __hip_bfloat162*)h)[(size_t)s2 * 64 + lane];
        __hip_bfloat162 h3 = ((const __hip_bfloat162*)h)[(size_t)s3 * 64 + lane];
        ax0 += w0 * bf2f(h0.x); ay0 += w0 * bf2f(h0.y);
        ax1 += w1 * bf2f(h1.x); ay1 += w1 * bf2f(h1.y);
        ax0 += w2 * bf2f(h2v.x); ay0 += w2 * bf2f(h2v.y);
        ax1 += w3 * bf2f(h3.x); ay1 += w3 * bf2f(h3.y);
    }
    for (; j < m0; ++j) {
        int s = colsh[wv][j];
        float w = wsh[wv][j * 4 + head];
        __hip_bfloat162 hv = ((const __hip_bfloat162*)h)[(size_t)s * 64 + lane];
        ax0 += w * bf2f(hv.x); ay0 += w * bf2f(hv.y);
    }
    for (; j < deg; ++j) {  // rare overflow path
        int s = col[beg + j];
        float w = __expf(lrelu(a_s[s * 4 + head] + adh));
        __hip_bfloat162 hv = ((const __hip_bfloat162*)h)[(size_t)s * 64 + lane];
        ax0 += w * bf2f(hv.x); ay0 += w * bf2f(hv.y);
    }
    {
        __hip_bfloat162 hv = ((const __hip_bfloat162*)h)[(size_t)nn * 64 + lane];
        ax0 += wself * bf2f(hv.x); ay0 += wself * bf2f(hv.y);
    }
    float inv = 1.f / den;
    float vx = (ax0 + ax1) * inv + b1[c];
    float vy = (ay0 + ay1) * inv + b1[c + 1];

    float s1 = vx + vy, s2 = vx * vx + vy * vy;
#pragma unroll
    for (int m = 1; m < 64; m <<= 1) {
        s1 += __shfl_xor(s1, m, 64);
        s2 += __shfl_xor(s2, m, 64);
    }
    float mean = s1 * (1.f / 128.f);
    float var = s2 * (1.f / 128.f) - mean * mean;
    float r = rsqrtf(var + LN_EPS);
    float ox = fmaxf(0.f, (vx - mean) * r * gamma[c] + beta[c]);
    float oy = fmaxf(0.f, (vy - mean) * r * gamma[c + 1] + beta[c + 1]);
    if (n < N_NODES) *(float2*)&out[(size_t)n * 128 + c] = make_float2(ox, oy);
}

// ---------------- aggregation layer 2 ----------------
__global__ __launch_bounds__(256) void agg2_kernel(const __hip_bfloat16* __restrict__ h,
                                                   const float* __restrict__ a_s,
                                                   const float* __restrict__ a_d,
                                                   const int* __restrict__ row_ptr,
                                                   const int* __restrict__ col,
                                                   const float* __restrict__ b2,
                                                   const float* __restrict__ gamma,
                                                   const float* __restrict__ beta,
                                                   float* __restrict__ out) {
    __shared__ int colsh[4][CAP];
    __shared__ float wsh[4][CAP];
    int wv = threadIdx.x >> 6;
    int lane = threadIdx.x & 63;
    int n = blockIdx.x * 4 + wv;
    int nn = (n < N_NODES) ? n : N_NODES - 1;

    float adh = a_d[nn];
    int beg = row_ptr[nn], end = row_ptr[nn + 1];
    int deg = end - beg;

    float den = 0.f;
    for (int t = lane; t < deg; t += 64) {
        int s = col[beg + t];
        float w = __expf(lrelu(a_s[s] + adh));
        if (t < CAP) {
            colsh[wv][t] = s;
            wsh[wv][t] = w;
        }
        den += w;
    }
#pragma unroll
    for (int m = 1; m < 64; m <<= 1) den += __shfl_xor(den, m, 64);
    float wself = __expf(lrelu(a_s[nn] + adh));
    den += wself;

    __syncthreads();

    float a0 = 0.f, a1 = 0.f;
    int m0 = (deg < CAP) ? deg : CAP;
    int j = 0;
    for (; j + 3 < m0; j += 4) {
        int s0 = colsh[wv][j + 0], s1 = colsh[wv][j + 1];
        int s2 = colsh[wv][j + 2], s3 = colsh[wv][j + 3];
        float w0 = wsh[wv][j + 0], w1 = wsh[wv][j + 1];
        float w2 = wsh[wv][j + 2], w3 = wsh[wv][j + 3];
        a0 += w0 * bf2f(h[(size_t)s0 * 64 + lane]);
        a1 += w1 * bf2f(h[(size_t)s1 * 64 + lane]);
        a0 += w2 * bf2f(h[(size_t)s2 * 64 + lane]);
        a1 += w3 * bf2f(h[(size_t)s3 * 64 + lane]);
    }
    for (; j < m0; ++j) {
        a0 += wsh[wv][j] * bf2f(h[(size_t)colsh[wv][j] * 64 + lane]);
    }
    for (; j < deg; ++j) {  // rare overflow path
        int s = col[beg + j];
        float w = __expf(lrelu(a_s[s] + adh));
        a0 += w * bf2f(h[(size_t)s * 64 + lane]);
    }
    a0 += wself * bf2f(h[(size_t)nn * 64 + lane]);

    float v = (a0 + a1) / den + b2[lane];

    float s1 = v, s2 = v * v;
#pragma unroll
    for (int m = 1; m < 64; m <<= 1) {
        s1 += __shfl_xor(s1, m, 64);
        s2 += __shfl_xor(s2, m, 64);
    }
    float mean = s1 * (1.f / 64.f);
    float var = s2 * (1.f / 64.f) - mean * mean;
    float r = rsqrtf(var + LN_EPS);
    if (n < N_NODES) out[(size_t)n * 64 + lane] = (v - mean) * r * gamma[lane] + beta[lane];
}

// ---------------- host ----------------
extern "C" void kernel_launch(void* const* d_in, const int* in_sizes, int n_in,
                              void* d_out, int out_size, void* d_ws, size_t ws_size,
                              hipStream_t stream) {
    const float* x        = (const float*)d_in[0];
    const int*   ei       = (const int*)d_in[1];
    const float* W1       = (const float*)d_in[2];
    const float* att_src1 = (const float*)d_in[3];
    const float* att_dst1 = (const float*)d_in[4];
    const float* b1       = (const float*)d_in[5];
    const float* gamma1   = (const float*)d_in[6];
    const float* beta1    = (const float*)d_in[7];
    const float* W2       = (const float*)d_in[8];
    const float* att_src2 = (const float*)d_in[9];
    const float* att_dst2 = (const float*)d_in[10];
    const float* b2       = (const float*)d_in[11];
    const float* gamma2   = (const float*)d_in[12];
    const float* beta2    = (const float*)d_in[13];
    const int* src = ei;
    const int* dst = ei + N_EDGES;
    float* out = (float*)d_out;

    char* ws = (char*)d_ws;
    size_t off = 0;
    auto alloc = [&](size_t bytes) -> void* {
        void* p = ws + off;
        off += bytes;
        off = (off + 255) & ~(size_t)255;
        return p;
    };
    __hip_bfloat16* h1pre = (__hip_bfloat16*)alloc((size_t)N_NODES * 128 * 2);
    __hip_bfloat16* h2pre = (__hip_bfloat16*)alloc((size_t)N_NODES * 64 * 2);
    float* a_s1   = (float*)alloc((size_t)N_NODES * 4 * 4);
    float* a_d1   = (float*)alloc((size_t)N_NODES * 4 * 4);
    float* h1n    = (float*)alloc((size_t)N_NODES * 128 * 4);
    float* a_s2   = (float*)alloc((size_t)N_NODES * 4);
    float* a_d2   = (float*)alloc((size_t)N_NODES * 4);
    int* deg      = (int*)alloc((size_t)N_NODES * 4);
    int* row_ptr  = (int*)alloc((size_t)(N_NODES + 1) * 4);
    int* col      = (int*)alloc((size_t)N_EDGES * 4);
    int* cursor   = (int*)alloc((size_t)N_NODES * 4);
    int* bsum     = (int*)alloc((size_t)NB_SCAN * 4);
    int* boff     = (int*)alloc((size_t)NB_SCAN * 4);

    hipMemsetAsync(deg, 0, (size_t)N_NODES * 4, stream);
    hipMemsetAsync(cursor, 0, (size_t)N_NODES * 4, stream);

    const int EB = (N_EDGES + 255) / 256;
    const int NWB = (N_NODES + 3) / 4;  // one wave per node, 4 waves/block

    degree_kernel<<<EB, 256, 0, stream>>>(dst, deg);
    scan1_kernel<<<NB_SCAN, 256, 0, stream>>>(deg, row_ptr, bsum);
    scan2_kernel<<<1, 256, 0, stream>>>(bsum, boff);
    scan3_kernel<<<NB_SCAN, 256, 0, stream>>>(row_ptr, boff);
    scatter_kernel<<<EB, 256, 0, stream>>>(src, dst, row_ptr, cursor, col);

    // layer 1
    gemm_kernel<128, 128><<<(N_NODES + 127) / 128, 256, 0, stream>>>(x, W1, h1pre);
    att1_kernel<<<NWB, 256, 0, stream>>>(h1pre, att_src1, att_dst1, a_s1, a_d1);
    agg1_kernel<<<NWB, 256, 0, stream>>>(h1pre, a_s1, a_d1, row_ptr, col, b1, gamma1, beta1, h1n);

    // layer 2
    gemm_kernel<64, 256><<<(N_NODES + 255) / 256, 256, 0, stream>>>(h1n, W2, h2pre);
    att2_kernel<<<NWB, 256, 0, stream>>>(h2pre, att_src2, att_dst2, a_s2, a_d2);
    agg2_kernel<<<NWB, 256, 0, stream>>>(h2pre, a_s2, a_d2, row_ptr, col, b2, gamma2, beta2, out);
}

// Round 4
// 251.666 us; speedup vs baseline: 2.1343x; 1.3538x over previous
//
#include <hip/hip_runtime.h>
#include <hip/hip_bf16.h>
#include <math.h>

#define N_NODES 50000
#define N_EDGES 800000
#define HEADS 4
#define HID 32
#define D1 128
#define D2 64
#define NEG_SLOPE 0.2f
#define LN_EPS 1e-5f

#define NB_SCAN ((N_NODES + 255) / 256)  // 196
#define CAP 64
#define GB1 ((N_NODES + 127) / 128)      // 391 gemm blocks in fused K1
#define DEGB 784                          // degree blocks in K1 (grid-stride, ~4 edges/thread)

__device__ __forceinline__ float lrelu(float x) { return x > 0.f ? x : NEG_SLOPE * x; }
__device__ __forceinline__ float bf2f(__hip_bfloat16 v) { return __bfloat162float(v); }

// ---------------- K1: gemm1 (+att1 epilogue) fused with degree/rank ----------------
__global__ __launch_bounds__(256) void gemm1_att1_degree_kernel(
    const float* __restrict__ X, const float* __restrict__ W,
    __hip_bfloat16* __restrict__ Y,
    const float* __restrict__ att_src, const float* __restrict__ att_dst,
    float* __restrict__ a_s, float* __restrict__ a_d,
    const int* __restrict__ dst, int* __restrict__ deg, int* __restrict__ rank) {
    if (blockIdx.x >= GB1) {
        // degree + rank part: 4 independent atomics in flight per thread
        int t0 = (blockIdx.x - GB1) * 256 + threadIdx.x;
        const int stride = DEGB * 256;
#pragma unroll
        for (int u = 0; u < 4; ++u) {
            int i = t0 + u * stride;
            if (i < N_EDGES) rank[i] = atomicAdd(&deg[dst[i]], 1);
        }
        return;
    }
    // gemm part: COLS=128, ROWS_PER_BLOCK=128, CG=8, RG=32, RPT=4
    constexpr int COLS = 128;
    constexpr int CG = 8, RPT = 4;
    __shared__ float Wlds[128 * COLS];
    for (int i = threadIdx.x; i < 128 * COLS; i += 256) Wlds[i] = W[i];
    __syncthreads();

    int cg = threadIdx.x % CG;
    int rg = threadIdx.x / CG;
    int r0 = blockIdx.x * 128 + rg * RPT;
    int c0 = cg * 16;

    float acc[RPT][16];
#pragma unroll
    for (int i = 0; i < RPT; ++i)
#pragma unroll
        for (int j = 0; j < 16; ++j) acc[i][j] = 0.f;

    const float* xrow[RPT];
#pragma unroll
    for (int i = 0; i < RPT; ++i) {
        int ri = r0 + i;
        if (ri >= N_NODES) ri = N_NODES - 1;
        xrow[i] = X + (size_t)ri * 128;
    }

    for (int k = 0; k < 128; k += 4) {
        float4 xv[RPT];
#pragma unroll
        for (int i = 0; i < RPT; ++i) xv[i] = *(const float4*)&xrow[i][k];
#pragma unroll
        for (int kk = 0; kk < 4; ++kk) {
            const float* wrow = &Wlds[(k + kk) * COLS + c0];
            const float4 w0 = *(const float4*)(wrow + 0);
            const float4 w1 = *(const float4*)(wrow + 4);
            const float4 w2 = *(const float4*)(wrow + 8);
            const float4 w3 = *(const float4*)(wrow + 12);
#pragma unroll
            for (int i = 0; i < RPT; ++i) {
                float xk = (kk == 0) ? xv[i].x : (kk == 1) ? xv[i].y : (kk == 2) ? xv[i].z : xv[i].w;
                acc[i][0]  += xk * w0.x; acc[i][1]  += xk * w0.y;
                acc[i][2]  += xk * w0.z; acc[i][3]  += xk * w0.w;
                acc[i][4]  += xk * w1.x; acc[i][5]  += xk * w1.y;
                acc[i][6]  += xk * w1.z; acc[i][7]  += xk * w1.w;
                acc[i][8]  += xk * w2.x; acc[i][9]  += xk * w2.y;
                acc[i][10] += xk * w2.z; acc[i][11] += xk * w2.w;
                acc[i][12] += xk * w3.x; acc[i][13] += xk * w3.y;
                acc[i][14] += xk * w3.z; acc[i][15] += xk * w3.w;
            }
        }
    }

    // epilogue: bf16 store + att1 coefficients
    int head = cg >> 1;
    int half = cg & 1;
    float asv[16], adv[16];
#pragma unroll
    for (int j = 0; j < 16; ++j) {
        asv[j] = att_src[head * 32 + half * 16 + j];
        adv[j] = att_dst[head * 32 + half * 16 + j];
    }
#pragma unroll
    for (int i = 0; i < RPT; ++i) {
        int r = r0 + i;
        float ps = 0.f, pd = 0.f;
#pragma unroll
        for (int j = 0; j < 16; ++j) {
            ps += acc[i][j] * asv[j];
            pd += acc[i][j] * adv[j];
        }
        ps += __shfl_xor(ps, 1, 64);
        pd += __shfl_xor(pd, 1, 64);
        if (r < N_NODES) {
            __hip_bfloat162* yp = (__hip_bfloat162*)(Y + (size_t)r * COLS + c0);
#pragma unroll
            for (int j = 0; j < 8; ++j) {
                __hip_bfloat162 p;
                p.x = __float2bfloat16(acc[i][2 * j]);
                p.y = __float2bfloat16(acc[i][2 * j + 1]);
                yp[j] = p;
            }
            if (half == 0) {
                a_s[r * 4 + head] = ps;
                a_d[r * 4 + head] = pd;
            }
        }
    }
}

// ---------------- scans ----------------
__global__ __launch_bounds__(256) void scan1_kernel(const int* __restrict__ deg,
                                                    int* __restrict__ rpl,
                                                    int* __restrict__ bsum) {
    int i = blockIdx.x * 256 + threadIdx.x;
    int v = (i < N_NODES) ? deg[i] : 0;
    int lane = threadIdx.x & 63;
    int w = threadIdx.x >> 6;
    int x = v;
#pragma unroll
    for (int off = 1; off < 64; off <<= 1) {
        int t = __shfl_up(x, off, 64);
        if (lane >= off) x += t;
    }
    __shared__ int wsum[4];
    if (lane == 63) wsum[w] = x;
    __syncthreads();
    int wo = 0;
    if (w > 0) wo += wsum[0];
    if (w > 1) wo += wsum[1];
    if (w > 2) wo += wsum[2];
    if (i <= N_NODES) rpl[i] = x - v + wo;  // local exclusive (incl. i==N_NODES)
    if (threadIdx.x == 255) bsum[blockIdx.x] = x + wo;
}

__global__ __launch_bounds__(256) void scan2_kernel(const int* __restrict__ bsum,
                                                    int* __restrict__ boff) {
    int i = threadIdx.x;
    int v = (i < NB_SCAN) ? bsum[i] : 0;
    int lane = threadIdx.x & 63;
    int w = threadIdx.x >> 6;
    int x = v;
#pragma unroll
    for (int off = 1; off < 64; off <<= 1) {
        int t = __shfl_up(x, off, 64);
        if (lane >= off) x += t;
    }
    __shared__ int wsum[4];
    if (lane == 63) wsum[w] = x;
    __syncthreads();
    int wo = 0;
    if (w > 0) wo += wsum[0];
    if (w > 1) wo += wsum[1];
    if (w > 2) wo += wsum[2];
    if (i < NB_SCAN) boff[i] = x - v + wo;
}

// ---------------- scatter (no atomics: rank precomputed) ----------------
__global__ __launch_bounds__(256) void scatter_kernel(const int* __restrict__ src,
                                                      const int* __restrict__ dst,
                                                      const int* __restrict__ rpl,
                                                      const int* __restrict__ boff,
                                                      const int* __restrict__ rank,
                                                      int* __restrict__ col) {
    int i = blockIdx.x * blockDim.x + threadIdx.x;
    if (i < N_EDGES) {
        int d = dst[i];
        int pos = rpl[d] + boff[d >> 8] + rank[i];
        col[pos] = src[i];
    }
}

// ---------------- aggregation layer 1 ----------------
__global__ __launch_bounds__(256) void agg1_kernel(const __hip_bfloat16* __restrict__ h,
                                                   const float* __restrict__ a_s,
                                                   const float* __restrict__ a_d,
                                                   const int* __restrict__ rpl,
                                                   const int* __restrict__ boff,
                                                   const int* __restrict__ col,
                                                   const float* __restrict__ b1,
                                                   const float* __restrict__ gamma,
                                                   const float* __restrict__ beta,
                                                   float* __restrict__ out) {
    __shared__ int colsh[4][CAP];
    __shared__ float wsh[4][CAP * 4];
    int wv = threadIdx.x >> 6;
    int lane = threadIdx.x & 63;
    int n = blockIdx.x * 4 + wv;
    int nn = (n < N_NODES) ? n : N_NODES - 1;
    int head = lane >> 4;
    int c = 2 * lane;

    const float4 ad4 = *(const float4*)&a_d[nn * 4];
    int beg = rpl[nn] + boff[nn >> 8];
    int end = rpl[nn + 1] + boff[(nn + 1) >> 8];
    int deg = end - beg;

    float den0 = 0.f, den1 = 0.f, den2 = 0.f, den3 = 0.f;
    for (int t = lane; t < deg; t += 64) {
        int s = col[beg + t];
        const float4 as4 = *(const float4*)&a_s[s * 4];
        float w0 = __expf(lrelu(as4.x + ad4.x));
        float w1 = __expf(lrelu(as4.y + ad4.y));
        float w2 = __expf(lrelu(as4.z + ad4.z));
        float w3 = __expf(lrelu(as4.w + ad4.w));
        if (t < CAP) {
            colsh[wv][t] = s;
            *(float4*)&wsh[wv][t * 4] = make_float4(w0, w1, w2, w3);
        }
        den0 += w0; den1 += w1; den2 += w2; den3 += w3;
    }
#pragma unroll
    for (int m = 1; m < 64; m <<= 1) {
        den0 += __shfl_xor(den0, m, 64);
        den1 += __shfl_xor(den1, m, 64);
        den2 += __shfl_xor(den2, m, 64);
        den3 += __shfl_xor(den3, m, 64);
    }
    float adh = (head == 0) ? ad4.x : (head == 1) ? ad4.y : (head == 2) ? ad4.z : ad4.w;
    float wself = __expf(lrelu(a_s[nn * 4 + head] + adh));
    float den = ((head == 0) ? den0 : (head == 1) ? den1 : (head == 2) ? den2 : den3) + wself;

    __syncthreads();

    float ax0 = 0.f, ay0 = 0.f, ax1 = 0.f, ay1 = 0.f;
    int m0 = (deg < CAP) ? deg : CAP;
    int j = 0;
    for (; j + 3 < m0; j += 4) {
        int s0 = colsh[wv][j + 0], s1 = colsh[wv][j + 1];
        int s2 = colsh[wv][j + 2], s3 = colsh[wv][j + 3];
        float w0 = wsh[wv][(j + 0) * 4 + head], w1 = wsh[wv][(j + 1) * 4 + head];
        float w2 = wsh[wv][(j + 2) * 4 + head], w3 = wsh[wv][(j + 3) * 4 + head];
        __hip_bfloat162 h0 = ((const __hip_bfloat162*)h)[(size_t)s0 * 64 + lane];
        __hip_bfloat162 h1 = ((const __hip_bfloat162*)h)[(size_t)s1 * 64 + lane];
        __hip_bfloat162 h2v = ((const __hip_bfloat162*)h)[(size_t)s2 * 64 + lane];
        __hip_bfloat162 h3 = ((const __hip_bfloat162*)h)[(size_t)s3 * 64 + lane];
        ax0 += w0 * bf2f(h0.x); ay0 += w0 * bf2f(h0.y);
        ax1 += w1 * bf2f(h1.x); ay1 += w1 * bf2f(h1.y);
        ax0 += w2 * bf2f(h2v.x); ay0 += w2 * bf2f(h2v.y);
        ax1 += w3 * bf2f(h3.x); ay1 += w3 * bf2f(h3.y);
    }
    for (; j < m0; ++j) {
        int s = colsh[wv][j];
        float w = wsh[wv][j * 4 + head];
        __hip_bfloat162 hv = ((const __hip_bfloat162*)h)[(size_t)s * 64 + lane];
        ax0 += w * bf2f(hv.x); ay0 += w * bf2f(hv.y);
    }
    for (; j < deg; ++j) {
        int s = col[beg + j];
        float w = __expf(lrelu(a_s[s * 4 + head] + adh));
        __hip_bfloat162 hv = ((const __hip_bfloat162*)h)[(size_t)s * 64 + lane];
        ax0 += w * bf2f(hv.x); ay0 += w * bf2f(hv.y);
    }
    {
        __hip_bfloat162 hv = ((const __hip_bfloat162*)h)[(size_t)nn * 64 + lane];
        ax0 += wself * bf2f(hv.x); ay0 += wself * bf2f(hv.y);
    }
    float inv = 1.f / den;
    float vx = (ax0 + ax1) * inv + b1[c];
    float vy = (ay0 + ay1) * inv + b1[c + 1];

    float s1 = vx + vy, s2 = vx * vx + vy * vy;
#pragma unroll
    for (int m = 1; m < 64; m <<= 1) {
        s1 += __shfl_xor(s1, m, 64);
        s2 += __shfl_xor(s2, m, 64);
    }
    float mean = s1 * (1.f / 128.f);
    float var = s2 * (1.f / 128.f) - mean * mean;
    float r = rsqrtf(var + LN_EPS);
    float ox = fmaxf(0.f, (vx - mean) * r * gamma[c] + beta[c]);
    float oy = fmaxf(0.f, (vy - mean) * r * gamma[c + 1] + beta[c + 1]);
    if (n < N_NODES) *(float2*)&out[(size_t)n * 128 + c] = make_float2(ox, oy);
}

// ---------------- gemm2 + att2 epilogue ----------------
__global__ __launch_bounds__(256) void gemm2_att2_kernel(const float* __restrict__ X,
                                                         const float* __restrict__ W,
                                                         __hip_bfloat16* __restrict__ Y,
                                                         const float* __restrict__ att_src,
                                                         const float* __restrict__ att_dst,
                                                         float* __restrict__ a_s,
                                                         float* __restrict__ a_d) {
    // COLS=64, ROWS_PER_BLOCK=128, CG=4, RG=64, RPT=2
    constexpr int COLS = 64;
    constexpr int CG = 4, RPT = 2;
    __shared__ float Wlds[128 * COLS];
    for (int i = threadIdx.x; i < 128 * COLS; i += 256) Wlds[i] = W[i];
    __syncthreads();

    int cg = threadIdx.x % CG;
    int rg = threadIdx.x / CG;
    int r0 = blockIdx.x * 128 + rg * RPT;
    int c0 = cg * 16;

    float acc[RPT][16];
#pragma unroll
    for (int i = 0; i < RPT; ++i)
#pragma unroll
        for (int j = 0; j < 16; ++j) acc[i][j] = 0.f;

    const float* xrow[RPT];
#pragma unroll
    for (int i = 0; i < RPT; ++i) {
        int ri = r0 + i;
        if (ri >= N_NODES) ri = N_NODES - 1;
        xrow[i] = X + (size_t)ri * 128;
    }

    for (int k = 0; k < 128; k += 4) {
        float4 xv[RPT];
#pragma unroll
        for (int i = 0; i < RPT; ++i) xv[i] = *(const float4*)&xrow[i][k];
#pragma unroll
        for (int kk = 0; kk < 4; ++kk) {
            const float* wrow = &Wlds[(k + kk) * COLS + c0];
            const float4 w0 = *(const float4*)(wrow + 0);
            const float4 w1 = *(const float4*)(wrow + 4);
            const float4 w2 = *(const float4*)(wrow + 8);
            const float4 w3 = *(const float4*)(wrow + 12);
#pragma unroll
            for (int i = 0; i < RPT; ++i) {
                float xk = (kk == 0) ? xv[i].x : (kk == 1) ? xv[i].y : (kk == 2) ? xv[i].z : xv[i].w;
                acc[i][0]  += xk * w0.x; acc[i][1]  += xk * w0.y;
                acc[i][2]  += xk * w0.z; acc[i][3]  += xk * w0.w;
                acc[i][4]  += xk * w1.x; acc[i][5]  += xk * w1.y;
                acc[i][6]  += xk * w1.z; acc[i][7]  += xk * w1.w;
                acc[i][8]  += xk * w2.x; acc[i][9]  += xk * w2.y;
                acc[i][10] += xk * w2.z; acc[i][11] += xk * w2.w;
                acc[i][12] += xk * w3.x; acc[i][13] += xk * w3.y;
                acc[i][14] += xk * w3.z; acc[i][15] += xk * w3.w;
            }
        }
    }

    float asv[16], adv[16];
#pragma unroll
    for (int j = 0; j < 16; ++j) {
        asv[j] = att_src[c0 + j];
        adv[j] = att_dst[c0 + j];
    }
#pragma unroll
    for (int i = 0; i < RPT; ++i) {
        int r = r0 + i;
        float ps = 0.f, pd = 0.f;
#pragma unroll
        for (int j = 0; j < 16; ++j) {
            ps += acc[i][j] * asv[j];
            pd += acc[i][j] * adv[j];
        }
        ps += __shfl_xor(ps, 1, 64);
        pd += __shfl_xor(pd, 1, 64);
        ps += __shfl_xor(ps, 2, 64);
        pd += __shfl_xor(pd, 2, 64);
        if (r < N_NODES) {
            __hip_bfloat162* yp = (__hip_bfloat162*)(Y + (size_t)r * COLS + c0);
#pragma unroll
            for (int j = 0; j < 8; ++j) {
                __hip_bfloat162 p;
                p.x = __float2bfloat16(acc[i][2 * j]);
                p.y = __float2bfloat16(acc[i][2 * j + 1]);
                yp[j] = p;
            }
            if (cg == 0) {
                a_s[r] = ps;
                a_d[r] = pd;
            }
        }
    }
}

// ---------------- aggregation layer 2 ----------------
__global__ __launch_bounds__(256) void agg2_kernel(const __hip_bfloat16* __restrict__ h,
                                                   const float* __restrict__ a_s,
                                                   const float* __restrict__ a_d,
                                                   const int* __restrict__ rpl,
                                                   const int* __restrict__ boff,
                                                   const int* __restrict__ col,
                                                   const float* __restrict__ b2,
                                                   const float* __restrict__ gamma,
                                                   const float* __restrict__ beta,
                                                   float* __restrict__ out) {
    __shared__ int colsh[4][CAP];
    __shared__ float wsh[4][CAP];
    int wv = threadIdx.x >> 6;
    int lane = threadIdx.x & 63;
    int n = blockIdx.x * 4 + wv;
    int nn = (n < N_NODES) ? n : N_NODES - 1;

    float adh = a_d[nn];
    int beg = rpl[nn] + boff[nn >> 8];
    int end = rpl[nn + 1] + boff[(nn + 1) >> 8];
    int deg = end - beg;

    float den = 0.f;
    for (int t = lane; t < deg; t += 64) {
        int s = col[beg + t];
        float w = __expf(lrelu(a_s[s] + adh));
        if (t < CAP) {
            colsh[wv][t] = s;
            wsh[wv][t] = w;
        }
        den += w;
    }
#pragma unroll
    for (int m = 1; m < 64; m <<= 1) den += __shfl_xor(den, m, 64);
    float wself = __expf(lrelu(a_s[nn] + adh));
    den += wself;

    __syncthreads();

    float a0 = 0.f, a1 = 0.f;
    int m0 = (deg < CAP) ? deg : CAP;
    int j = 0;
    for (; j + 3 < m0; j += 4) {
        int s0 = colsh[wv][j + 0], s1 = colsh[wv][j + 1];
        int s2 = colsh[wv][j + 2], s3 = colsh[wv][j + 3];
        float w0 = wsh[wv][j + 0], w1 = wsh[wv][j + 1];
        float w2 = wsh[wv][j + 2], w3 = wsh[wv][j + 3];
        a0 += w0 * bf2f(h[(size_t)s0 * 64 + lane]);
        a1 += w1 * bf2f(h[(size_t)s1 * 64 + lane]);
        a0 += w2 * bf2f(h[(size_t)s2 * 64 + lane]);
        a1 += w3 * bf2f(h[(size_t)s3 * 64 + lane]);
    }
    for (; j < m0; ++j) {
        a0 += wsh[wv][j] * bf2f(h[(size_t)colsh[wv][j] * 64 + lane]);
    }
    for (; j < deg; ++j) {
        int s = col[beg + j];
        float w = __expf(lrelu(a_s[s] + adh));
        a0 += w * bf2f(h[(size_t)s * 64 + lane]);
    }
    a0 += wself * bf2f(h[(size_t)nn * 64 + lane]);

    float v = (a0 + a1) / den + b2[lane];

    float s1 = v, s2 = v * v;
#pragma unroll
    for (int m = 1; m < 64; m <<= 1) {
        s1 += __shfl_xor(s1, m, 64);
        s2 += __shfl_xor(s2, m, 64);
    }
    float mean = s1 * (1.f / 64.f);
    float var = s2 * (1.f / 64.f) - mean * mean;
    float r = rsqrtf(var + LN_EPS);
    if (n < N_NODES) out[(size_t)n * 64 + lane] = (v - mean) * r * gamma[lane] + beta[lane];
}

// ---------------- host ----------------
extern "C" void kernel_launch(void* const* d_in, const int* in_sizes, int n_in,
                              void* d_out, int out_size, void* d_ws, size_t ws_size,
                              hipStream_t stream) {
    const float* x        = (const float*)d_in[0];
    const int*   ei       = (const int*)d_in[1];
    const float* W1       = (const float*)d_in[2];
    const float* att_src1 = (const float*)d_in[3];
    const float* att_dst1 = (const float*)d_in[4];
    const float* b1       = (const float*)d_in[5];
    const float* gamma1   = (const float*)d_in[6];
    const float* beta1    = (const float*)d_in[7];
    const float* W2       = (const float*)d_in[8];
    const float* att_src2 = (const float*)d_in[9];
    const float* att_dst2 = (const float*)d_in[10];
    const float* b2       = (const float*)d_in[11];
    const float* gamma2   = (const float*)d_in[12];
    const float* beta2    = (const float*)d_in[13];
    const int* src = ei;
    const int* dst = ei + N_EDGES;
    float* out = (float*)d_out;

    char* ws = (char*)d_ws;
    size_t off = 0;
    auto alloc = [&](size_t bytes) -> void* {
        void* p = ws + off;
        off += bytes;
        off = (off + 255) & ~(size_t)255;
        return p;
    };
    __hip_bfloat16* h1pre = (__hip_bfloat16*)alloc((size_t)N_NODES * 128 * 2);
    __hip_bfloat16* h2pre = (__hip_bfloat16*)alloc((size_t)N_NODES * 64 * 2);
    float* a_s1   = (float*)alloc((size_t)N_NODES * 4 * 4);
    float* a_d1   = (float*)alloc((size_t)N_NODES * 4 * 4);
    float* h1n    = (float*)alloc((size_t)N_NODES * 128 * 4);
    float* a_s2   = (float*)alloc((size_t)N_NODES * 4);
    float* a_d2   = (float*)alloc((size_t)N_NODES * 4);
    int* deg      = (int*)alloc((size_t)N_NODES * 4);
    int* rpl      = (int*)alloc((size_t)(N_NODES + 1) * 4);
    int* col      = (int*)alloc((size_t)N_EDGES * 4);
    int* rank     = (int*)alloc((size_t)N_EDGES * 4);
    int* bsum     = (int*)alloc((size_t)NB_SCAN * 4);
    int* boff     = (int*)alloc((size_t)NB_SCAN * 4);

    hipMemsetAsync(deg, 0, (size_t)N_NODES * 4, stream);

    const int EB = (N_EDGES + 255) / 256;
    const int NWB = (N_NODES + 3) / 4;

    // K1: gemm1 + att1 epilogue + degree/rank
    gemm1_att1_degree_kernel<<<GB1 + DEGB, 256, 0, stream>>>(
        x, W1, h1pre, att_src1, att_dst1, a_s1, a_d1, dst, deg, rank);
    scan1_kernel<<<NB_SCAN, 256, 0, stream>>>(deg, rpl, bsum);
    scan2_kernel<<<1, 256, 0, stream>>>(bsum, boff);
    scatter_kernel<<<EB, 256, 0, stream>>>(src, dst, rpl, boff, rank, col);

    agg1_kernel<<<NWB, 256, 0, stream>>>(h1pre, a_s1, a_d1, rpl, boff, col, b1, gamma1, beta1, h1n);

    gemm2_att2_kernel<<<(N_NODES + 127) / 128, 256, 0, stream>>>(
        h1n, W2, h2pre, att_src2, att_dst2, a_s2, a_d2);
    agg2_kernel<<<NWB, 256, 0, stream>>>(h2pre, a_s2, a_d2, rpl, boff, col, b2, gamma2, beta2, out);
}